// Round 1
// baseline (943.152 us; speedup 1.0000x reference)
//
#include <hip/hip_runtime.h>
#include <math.h>

typedef __attribute__((ext_vector_type(8))) short bf16x8;
typedef __attribute__((ext_vector_type(4))) float f32x4;

#define TM 19
#define NV 30000

__device__ __forceinline__ float bf2f(unsigned short u){
  union { unsigned int i; float f; } v; v.i = ((unsigned int)u) << 16; return v.f;
}
__device__ __forceinline__ unsigned short f2bf(float f){
  union { float f; unsigned int i; } v; v.f = f;
  unsigned int x = v.i;
  unsigned int r = (x + 0x7fffu + ((x >> 16) & 1u)) >> 16;
  return (unsigned short)r;
}

// ---------------- sort (stable descending argsort of lengths) ----------------
__global__ void k_sort(const int* __restrict__ lengths, const int* __restrict__ captions,
                       int* __restrict__ sort_ws, int* __restrict__ dl_ws, int* __restrict__ caps_ws,
                       float* __restrict__ out_caps, float* __restrict__ out_dl, float* __restrict__ out_sort){
  int b = threadIdx.x; // 64 threads
  __shared__ int len_s[64];
  len_s[b] = lengths[b];
  __syncthreads();
  int lb = len_s[b];
  int r = 0;
  for(int j = 0; j < 64; j++){
    int lj = len_s[j];
    r += (lj > lb) || (lj == lb && j < b);
  }
  sort_ws[r] = b;
  dl_ws[r] = lb - 1;
  out_sort[r] = (float)b;
  out_dl[r] = (float)(lb - 1);
  for(int tt = 0; tt < 20; tt++){
    int c = captions[b*20 + tt];
    caps_ws[r*20 + tt] = c;
    out_caps[r*20 + tt] = (float)c;
  }
}

// ---------------- f32 -> bf16 convert, 4 elems/thread ----------------
__global__ void k_cvt4(const float4* __restrict__ src, ushort4* __restrict__ dst, int n4){
  int i = blockIdx.x*256 + threadIdx.x;
  if(i < n4){
    float4 v = src[i];
    ushort4 o; o.x = f2bf(v.x); o.y = f2bf(v.y); o.z = f2bf(v.z); o.w = f2bf(v.w);
    dst[i] = o;
  }
}

// ---------------- gather+convert sorted features ----------------
__global__ void k_feats(const float* __restrict__ feats, const int* __restrict__ sort_ws,
                        unsigned short* __restrict__ feats_bf){
  int rp = blockIdx.x; // 3136 = r*49+p
  int r = rp / 49, p = rp % 49;
  int sb = sort_ws[r];
  const float* src = feats + ((size_t)sb*49 + p)*1024;
  unsigned short* dst = feats_bf + (size_t)rp*1024;
  int f = threadIdx.x*4;
  float4 v = *(const float4*)(src + f);
  ushort4 o; o.x = f2bf(v.x); o.y = f2bf(v.y); o.z = f2bf(v.z); o.w = f2bf(v.w);
  *(ushort4*)(dst + f) = o;
}

// ---------------- per-batch feature mean (fp32, sorted) ----------------
__global__ void k_featmean(const float* __restrict__ feats, const int* __restrict__ sort_ws,
                           float* __restrict__ fm){
  int r = blockIdx.x;
  int sb = sort_ws[r];
  const float* src = feats + (size_t)sb*49*1024;
  int f = threadIdx.x*4;
  float a0=0,a1=0,a2=0,a3=0;
  for(int p = 0; p < 49; p++){
    float4 v = *(const float4*)(src + p*1024 + f);
    a0 += v.x; a1 += v.y; a2 += v.z; a3 += v.w;
  }
  const float inv = 1.0f/49.0f;
  float4 o; o.x=a0*inv; o.y=a1*inv; o.z=a2*inv; o.w=a3*inv;
  *(float4*)(fm + r*1024 + f) = o;
}

// ---------------- h0 = fmean @ Winit.T + binit (fp32 GEMV-ish) ----------------
__global__ void k_h0(const float* __restrict__ fm, const float* __restrict__ Winit,
                     const float* __restrict__ binit,
                     float* __restrict__ h, unsigned short* __restrict__ h_bf){
  int idx = blockIdx.x*256 + threadIdx.x; // 32768 = 64*512
  int r = idx >> 9, n = idx & 511;
  const float* a = fm + r*1024;
  const float* wrow = Winit + (size_t)n*1024;
  float s = 0.f;
  for(int k = 0; k < 1024; k += 4){
    float4 av = *(const float4*)(a + k);
    float4 wv = *(const float4*)(wrow + k);
    s += av.x*wv.x + av.y*wv.y + av.z*wv.z + av.w*wv.w;
  }
  s += binit[n];
  h[idx] = s;
  h_bf[idx] = f2bf(s);
}

// ---------------- embedding gather -> bf16, rows t*64+r ----------------
__global__ void k_embs(const float* __restrict__ emb, const int* __restrict__ caps_ws,
                       unsigned short* __restrict__ embs_bf){
  int row = blockIdx.x; // 1216
  int t = row >> 6, r = row & 63;
  int cap = caps_ws[r*20 + t];
  const float* src = emb + (size_t)cap*512;
  unsigned short* dst = embs_bf + (size_t)row*512;
  int e = threadIdx.x*2;
  float2 v = *(const float2*)(src + e);
  dst[e]   = f2bf(v.x);
  dst[e+1] = f2bf(v.y);
}

// ---------------- generic 64x64-tile bf16 MFMA GEMM, C = A @ B^T, split-K via z ----------------
// A: M x K (row-major, lda), Bm: N x K (row-major, ldb). C partial z at C + z*M*ldc (M=gridDim.y*64).
__global__ __launch_bounds__(256) void k_gemm64(
    const unsigned short* __restrict__ A, int lda,
    const unsigned short* __restrict__ Bm, int ldb,
    float* __restrict__ C, int ldc, int Ksplit){
  __shared__ unsigned short As[64*40];
  __shared__ unsigned short Bs[64*40];
  int tid = threadIdx.x;
  int wave = tid >> 6, lane = tid & 63;
  int m0 = blockIdx.y*64, n0 = blockIdx.x*64;
  int k0 = blockIdx.z*Ksplit;
  int lrow = tid >> 2, lcol = (tid & 3)*8;
  const unsigned short* Ag = A + (size_t)(m0 + lrow)*lda + k0 + lcol;
  const unsigned short* Bg = Bm + (size_t)(n0 + lrow)*ldb + k0 + lcol;
  f32x4 acc0 = {0,0,0,0}, acc1 = {0,0,0,0}, acc2 = {0,0,0,0}, acc3 = {0,0,0,0};
  int quad = lane >> 4;
  int mrow = (wave << 4) + (lane & 15);
  for(int kk = 0; kk < Ksplit; kk += 32){
    uint4 av = *(const uint4*)(Ag + kk);
    uint4 bv = *(const uint4*)(Bg + kk);
    __syncthreads();
    *(uint4*)(&As[lrow*40 + lcol]) = av;
    *(uint4*)(&Bs[lrow*40 + lcol]) = bv;
    __syncthreads();
    bf16x8 a = *(const bf16x8*)(&As[mrow*40 + quad*8]);
    bf16x8 b0 = *(const bf16x8*)(&Bs[( 0 + (lane & 15))*40 + quad*8]);
    bf16x8 b1 = *(const bf16x8*)(&Bs[(16 + (lane & 15))*40 + quad*8]);
    bf16x8 b2 = *(const bf16x8*)(&Bs[(32 + (lane & 15))*40 + quad*8]);
    bf16x8 b3 = *(const bf16x8*)(&Bs[(48 + (lane & 15))*40 + quad*8]);
    acc0 = __builtin_amdgcn_mfma_f32_16x16x32_bf16(a, b0, acc0, 0, 0, 0);
    acc1 = __builtin_amdgcn_mfma_f32_16x16x32_bf16(a, b1, acc1, 0, 0, 0);
    acc2 = __builtin_amdgcn_mfma_f32_16x16x32_bf16(a, b2, acc2, 0, 0, 0);
    acc3 = __builtin_amdgcn_mfma_f32_16x16x32_bf16(a, b3, acc3, 0, 0, 0);
  }
  float* Cb = C + (size_t)blockIdx.z * ((size_t)gridDim.y*64*ldc);
  int col = lane & 15;
  #pragma unroll
  for(int rg = 0; rg < 4; rg++){
    int m = m0 + (wave << 4) + quad*4 + rg;
    float* crow = Cb + (size_t)m*ldc + n0 + col;
    crow[0]  = acc0[rg];
    crow[16] = acc1[rg];
    crow[32] = acc2[rg];
    crow[48] = acc3[rg];
  }
}

// ---------------- attention + softmax + awe + gate + x_awe (one block per r) ----------------
__global__ __launch_bounds__(256) void k_attn(
    const float* __restrict__ att1, const float* __restrict__ y1p,
    const float* __restrict__ bd, const float* __restrict__ be,
    const float* __restrict__ Wf, const float* __restrict__ bfb,
    const float* __restrict__ bbeta,
    const unsigned short* __restrict__ feats_bf,
    const int* __restrict__ dl_ws,
    unsigned short* __restrict__ x_awe, float* __restrict__ out_alph, int t){
  int r = blockIdx.x;
  int tid = threadIdx.x;
  __shared__ float att2s[512];
  __shared__ float es[64];
  __shared__ float alph[49];
  const float* y0 = y1p + (size_t)r*3072;
  const float* y1 = y1p + (size_t)64*3072 + (size_t)r*3072;
  for(int k = tid; k < 512; k += 256) att2s[k] = y0[k] + y1[k] + bd[k] + be[k];
  __syncthreads();
  int wave = tid >> 6, lane = tid & 63;
  for(int p = wave; p < 49; p += 4){
    const float* arow = att1 + ((size_t)r*49 + p)*512;
    float s = 0.f;
    #pragma unroll
    for(int i = 0; i < 8; i++){
      int k = lane + i*64;
      float v = arow[k] + att2s[k];
      s += fmaxf(v, 0.f) * Wf[k];
    }
    #pragma unroll
    for(int off = 32; off; off >>= 1) s += __shfl_xor(s, off, 64);
    if(lane == 0) es[p] = s + bfb[0];
  }
  __syncthreads();
  if(wave == 0){
    float v = (lane < 49) ? es[lane] : -1e30f;
    float m = v;
    #pragma unroll
    for(int off = 32; off; off >>= 1) m = fmaxf(m, __shfl_xor(m, off, 64));
    float ex = (lane < 49) ? __expf(v - m) : 0.f;
    float sm = ex;
    #pragma unroll
    for(int off = 32; off; off >>= 1) sm += __shfl_xor(sm, off, 64);
    float al = ex / sm;
    if(lane < 49){
      alph[lane] = al;
      bool act = t < dl_ws[r];
      out_alph[(size_t)r*(TM*49) + t*49 + lane] = act ? al : 0.f;
    }
  }
  __syncthreads();
  int f0 = tid*4;
  float a0=0,a1=0,a2=0,a3=0;
  const unsigned short* fr = feats_bf + (size_t)r*49*1024 + f0;
  for(int p = 0; p < 49; p++){
    float al = alph[p];
    ushort4 v = *(const ushort4*)(fr + p*1024);
    a0 += al*bf2f(v.x); a1 += al*bf2f(v.y); a2 += al*bf2f(v.z); a3 += al*bf2f(v.w);
  }
  const float* g0 = y0 + 512;
  const float* g1 = y1 + 512;
  ushort4 xo;
  float gp;
  gp = g0[f0+0] + g1[f0+0] + bbeta[f0+0]; xo.x = f2bf(a0 / (1.f + __expf(-gp)));
  gp = g0[f0+1] + g1[f0+1] + bbeta[f0+1]; xo.y = f2bf(a1 / (1.f + __expf(-gp)));
  gp = g0[f0+2] + g1[f0+2] + bbeta[f0+2]; xo.z = f2bf(a2 / (1.f + __expf(-gp)));
  gp = g0[f0+3] + g1[f0+3] + bbeta[f0+3]; xo.w = f2bf(a3 / (1.f + __expf(-gp)));
  *(ushort4*)(x_awe + (size_t)r*1024 + f0) = xo;
}

// ---------------- GRU elementwise ----------------
__global__ __launch_bounds__(256) void k_gru(
    const float* __restrict__ gi_emb, const float* __restrict__ gip,
    const float* __restrict__ y1p,
    const float* __restrict__ bih, const float* __restrict__ bhh,
    const int* __restrict__ dl_ws,
    float* __restrict__ h, unsigned short* __restrict__ h_bf,
    unsigned short* __restrict__ hseq, int t){
  int idx = blockIdx.x*256 + threadIdx.x; // 32768
  int r = idx >> 9, j = idx & 511;
  const float* ge = gi_emb + (size_t)(t*64 + r)*1536;
  float ir = ge[j], iz = ge[512 + j], in_ = ge[1024 + j];
  #pragma unroll
  for(int s = 0; s < 4; s++){
    const float* gp = gip + (size_t)s*64*1536 + (size_t)r*1536;
    ir += gp[j]; iz += gp[512 + j]; in_ += gp[1024 + j];
  }
  ir += bih[j]; iz += bih[512 + j]; in_ += bih[1024 + j];
  float hr = bhh[j], hz = bhh[512 + j], hn = bhh[1024 + j];
  #pragma unroll
  for(int s = 0; s < 2; s++){
    const float* yp = y1p + (size_t)s*64*3072 + (size_t)r*3072 + 1536;
    hr += yp[j]; hz += yp[512 + j]; hn += yp[1024 + j];
  }
  float rg = 1.f / (1.f + __expf(-(ir + hr)));
  float zg = 1.f / (1.f + __expf(-(iz + hz)));
  float ng = tanhf(in_ + rg*hn);
  float hold = h[idx];
  float hnew = (1.f - zg)*ng + zg*hold;
  hseq[(size_t)t*32768 + idx] = f2bf(hnew);
  bool act = t < dl_ws[r];
  float hout = act ? hnew : hold;
  h[idx] = hout;
  h_bf[idx] = f2bf(hout);
}

// ---------------- final vocab projection: (1216x512)@(512x30000)^T + mask ----------------
__global__ __launch_bounds__(256) void k_preds(
    const unsigned short* __restrict__ hseq, const unsigned short* __restrict__ Wfc_bf,
    const float* __restrict__ bfc, const int* __restrict__ dl_ws,
    float* __restrict__ out_pred){
  __shared__ unsigned short As[64*40];
  __shared__ unsigned short Bs[64*40];
  int tid = threadIdx.x;
  int wave = tid >> 6, lane = tid & 63;
  int m0 = blockIdx.y*64, n0 = blockIdx.x*64;
  int lrow = tid >> 2, lcol = (tid & 3)*8;
  const unsigned short* Ag = hseq + (size_t)(m0 + lrow)*512 + lcol;
  int brow = n0 + lrow;
  bool bvalid = brow < NV;
  const unsigned short* Bg = Wfc_bf + (size_t)(bvalid ? brow : 0)*512 + lcol;
  f32x4 acc0 = {0,0,0,0}, acc1 = {0,0,0,0}, acc2 = {0,0,0,0}, acc3 = {0,0,0,0};
  int quad = lane >> 4;
  int mrow = (wave << 4) + (lane & 15);
  for(int kk = 0; kk < 512; kk += 32){
    uint4 av = *(const uint4*)(Ag + kk);
    uint4 bv;
    if(bvalid) bv = *(const uint4*)(Bg + kk);
    else { bv.x = 0; bv.y = 0; bv.z = 0; bv.w = 0; }
    __syncthreads();
    *(uint4*)(&As[lrow*40 + lcol]) = av;
    *(uint4*)(&Bs[lrow*40 + lcol]) = bv;
    __syncthreads();
    bf16x8 a = *(const bf16x8*)(&As[mrow*40 + quad*8]);
    bf16x8 b0 = *(const bf16x8*)(&Bs[( 0 + (lane & 15))*40 + quad*8]);
    bf16x8 b1 = *(const bf16x8*)(&Bs[(16 + (lane & 15))*40 + quad*8]);
    bf16x8 b2 = *(const bf16x8*)(&Bs[(32 + (lane & 15))*40 + quad*8]);
    bf16x8 b3 = *(const bf16x8*)(&Bs[(48 + (lane & 15))*40 + quad*8]);
    acc0 = __builtin_amdgcn_mfma_f32_16x16x32_bf16(a, b0, acc0, 0, 0, 0);
    acc1 = __builtin_amdgcn_mfma_f32_16x16x32_bf16(a, b1, acc1, 0, 0, 0);
    acc2 = __builtin_amdgcn_mfma_f32_16x16x32_bf16(a, b2, acc2, 0, 0, 0);
    acc3 = __builtin_amdgcn_mfma_f32_16x16x32_bf16(a, b3, acc3, 0, 0, 0);
  }
  int col = lane & 15;
  #pragma unroll
  for(int j = 0; j < 4; j++){
    int n = n0 + j*16 + col;
    if(n < NV){
      float bias = bfc[n];
      f32x4 acc = (j == 0) ? acc0 : (j == 1) ? acc1 : (j == 2) ? acc2 : acc3;
      #pragma unroll
      for(int rg = 0; rg < 4; rg++){
        int mr = m0 + (wave << 4) + quad*4 + rg;
        int t = mr >> 6, r = mr & 63;
        bool act = t < dl_ws[r];
        float v = act ? (acc[rg] + bias) : 0.f;
        out_pred[(size_t)r*((size_t)TM*NV) + (size_t)t*NV + n] = v;
      }
    }
  }
}

extern "C" void kernel_launch(void* const* d_in, const int* in_sizes, int n_in,
                              void* d_out, int out_size, void* d_ws, size_t ws_size,
                              hipStream_t stream){
  const float* features = (const float*)d_in[0];
  const int*   captions = (const int*)d_in[1];
  const int*   lengths  = (const int*)d_in[2];
  const float* We    = (const float*)d_in[3];
  const float* be    = (const float*)d_in[4];
  const float* Wd    = (const float*)d_in[5];
  const float* bd    = (const float*)d_in[6];
  const float* Wf    = (const float*)d_in[7];
  const float* bfb   = (const float*)d_in[8];
  const float* emb   = (const float*)d_in[9];
  const float* Wih   = (const float*)d_in[10];
  const float* Whh   = (const float*)d_in[11];
  const float* bih   = (const float*)d_in[12];
  const float* bhh   = (const float*)d_in[13];
  const float* Winit = (const float*)d_in[14];
  const float* binit = (const float*)d_in[15];
  const float* Wbeta = (const float*)d_in[16];
  const float* bbeta = (const float*)d_in[17];
  const float* Wfc   = (const float*)d_in[18];
  const float* bfc   = (const float*)d_in[19];

  float* out = (float*)d_out;
  float* out_pred = out;                 // 36,480,000
  float* out_caps = out + 36480000;      // 1,280
  float* out_dl   = out + 36481280;      // 64
  float* out_alph = out + 36481344;      // 59,584
  float* out_sort = out + 36540928;      // 64

  char* w = (char*)d_ws;
  auto alloc = [&](size_t bytes){ void* p = (void*)w; w += (bytes + 255) & ~(size_t)255; return p; };
  unsigned short* We_bf    = (unsigned short*)alloc((size_t)512*1024*2);
  unsigned short* W1_bf    = (unsigned short*)alloc((size_t)3072*512*2);   // [Wd;Wbeta;Whh]
  unsigned short* Wih_bf   = (unsigned short*)alloc((size_t)1536*1536*2);
  unsigned short* Wfc_bf   = (unsigned short*)alloc((size_t)NV*512*2);
  unsigned short* feats_bf = (unsigned short*)alloc((size_t)64*49*1024*2);
  unsigned short* embs_bf  = (unsigned short*)alloc((size_t)1216*512*2);
  unsigned short* hseq_bf  = (unsigned short*)alloc((size_t)1216*512*2);
  unsigned short* h_bf     = (unsigned short*)alloc((size_t)64*512*2);
  unsigned short* xawe_bf  = (unsigned short*)alloc((size_t)64*1024*2);
  float* att1   = (float*)alloc((size_t)3136*512*4);
  float* gi_emb = (float*)alloc((size_t)1216*1536*4);
  float* y1p    = (float*)alloc((size_t)2*64*3072*4);
  float* gip    = (float*)alloc((size_t)4*64*1536*4);
  float* hbuf   = (float*)alloc((size_t)64*512*4);
  float* fmean  = (float*)alloc((size_t)64*1024*4);
  int* sort_ws  = (int*)alloc(64*4);
  int* dl_ws    = (int*)alloc(64*4);
  int* caps_ws  = (int*)alloc(1280*4);
  (void)in_sizes; (void)n_in; (void)out_size; (void)ws_size;

  k_sort<<<1, 64, 0, stream>>>(lengths, captions, sort_ws, dl_ws, caps_ws, out_caps, out_dl, out_sort);

  k_cvt4<<<512,  256, 0, stream>>>((const float4*)We,    (ushort4*)We_bf,             512*1024/4);
  k_cvt4<<<256,  256, 0, stream>>>((const float4*)Wd,    (ushort4*)W1_bf,             512*512/4);
  k_cvt4<<<512,  256, 0, stream>>>((const float4*)Wbeta, (ushort4*)(W1_bf + 512*512), 1024*512/4);
  k_cvt4<<<768,  256, 0, stream>>>((const float4*)Whh,   (ushort4*)(W1_bf + 1536*512),1536*512/4);
  k_cvt4<<<2304, 256, 0, stream>>>((const float4*)Wih,   (ushort4*)Wih_bf,            1536*1536/4);
  k_cvt4<<<15000,256, 0, stream>>>((const float4*)Wfc,   (ushort4*)Wfc_bf,            NV*512/4);

  k_feats<<<3136, 256, 0, stream>>>(features, sort_ws, feats_bf);
  k_featmean<<<64, 256, 0, stream>>>(features, sort_ws, fmean);
  k_h0<<<128, 256, 0, stream>>>(fmean, Winit, binit, hbuf, h_bf);
  k_embs<<<1216, 256, 0, stream>>>(emb, caps_ws, embs_bf);

  // att1 = feats_s @ We^T : M=3136, N=512, K=1024
  k_gemm64<<<dim3(8, 49, 1), 256, 0, stream>>>(feats_bf, 1024, We_bf, 1024, att1, 512, 1024);
  // gi_emb = embs @ Wih[:, :512]^T : M=1216, N=1536, K=512
  k_gemm64<<<dim3(24, 19, 1), 256, 0, stream>>>(embs_bf, 512, Wih_bf, 1536, gi_emb, 1536, 512);

  for(int t = 0; t < TM; t++){
    // y1 = h @ [Wd;Wbeta;Whh]^T : M=64, N=3072, K=512 (split-K=2)
    k_gemm64<<<dim3(48, 1, 2), 256, 0, stream>>>(h_bf, 512, W1_bf, 512, y1p, 3072, 256);
    k_attn<<<64, 256, 0, stream>>>(att1, y1p, bd, be, Wf, bfb, bbeta, feats_bf, dl_ws, xawe_bf, out_alph, t);
    // gi_awe = x_awe @ Wih[:, 512:]^T : M=64, N=1536, K=1024 (split-K=4)
    k_gemm64<<<dim3(24, 1, 4), 256, 0, stream>>>(xawe_bf, 1024, Wih_bf + 512, 1536, gip, 1536, 256);
    k_gru<<<128, 256, 0, stream>>>(gi_emb, gip, y1p, bih, bhh, dl_ws, hbuf, h_bf, hseq_bf, t);
  }

  // predictions: (1216 x 512) @ (512 x 30000)^T, masked scatter to out
  k_preds<<<dim3(469, 19, 1), 256, 0, stream>>>(hseq_bf, Wfc_bf, bfc, dl_ws, out_pred);
}